// Round 1
// baseline (1858.937 us; speedup 1.0000x reference)
//
#include <hip/hip_runtime.h>
#include <math.h>

#define B_ 4
#define D_ 96
#define H_ 64
#define W_ 64
#define L_ 4096
#define K_ 4
#define N_ 16
#define R_ 6
#define C_ 38  // R + 2N

// Flat index into x[b,d,:,:] (H*W) for cross-scan direction k at sequence pos l.
// k=0: row-major; k=1: col-major (transpose); k=2/3: reversed versions.
__device__ __forceinline__ int src_idx(int k, int l) {
    int m = (k >= 2) ? (L_ - 1 - l) : l;
    if (k & 1) {
        // transpose map (H=W=64): m = w*H + h  ->  src = h*W + w
        return ((m & 63) << 6) | (m >> 6);
    }
    return m;
}

// ---------------------------------------------------------------------------
// Kernel A: projections. One block per (b, k, 64-wide l tile).
// Computes x_dbl = W_proj[k] @ xs_tile, then delta (softplus), Bs, Cs.
// Outputs: delta[bk][l][96], Bs[bk][l][16], Cs[bk][l][16]
// ---------------------------------------------------------------------------
__global__ __launch_bounds__(256) void proj_kernel(
    const float* __restrict__ x,     // (B,D,H,W)
    const float* __restrict__ xpw,   // (K,38,96)
    const float* __restrict__ wdt,   // (K,96,6)
    const float* __restrict__ bdt,   // (K,96)
    float* __restrict__ delta,       // (B*K, L, 96)
    float* __restrict__ Bsb,         // (B*K, L, 16)
    float* __restrict__ Csb)         // (B*K, L, 16)
{
    const int TL = 64;
    const int tiles = L_ / TL;               // 64
    int bid = blockIdx.x;                    // B*K*tiles = 1024
    int bk = bid / tiles;
    int tile = bid % tiles;
    int b = bk / K_, k = bk % K_;
    int l0 = tile * TL;
    int tid = threadIdx.x;

    __shared__ float s_wp[C_ * D_];          // [c][d]
    __shared__ float s_wdt[R_ * D_];         // transposed [r][d]
    __shared__ float s_bias[D_];
    __shared__ float s_xs[D_ * TL];          // [d][lt]
    __shared__ float s_xdbl[C_ * (TL + 1)];  // [c][lt], padded

    for (int i = tid; i < C_ * D_; i += 256) s_wp[i] = xpw[k * C_ * D_ + i];
    for (int i = tid; i < R_ * D_; i += 256) {
        int r = i / D_, d = i % D_;
        s_wdt[i] = wdt[(k * D_ + d) * R_ + r];
    }
    if (tid < D_) s_bias[tid] = bdt[k * D_ + tid];
    for (int i = tid; i < D_ * TL; i += 256) {
        int d = i / TL, lt = i % TL;
        s_xs[i] = x[(b * D_ + d) * L_ + src_idx(k, l0 + lt)];
    }
    __syncthreads();

    // x_dbl[c][lt] = sum_d W[c][d] * xs[d][lt]
    for (int idx = tid; idx < C_ * TL; idx += 256) {
        int c = idx / TL, lt = idx % TL;
        const float* wr = &s_wp[c * D_];
        float acc = 0.f;
#pragma unroll 8
        for (int d = 0; d < D_; ++d) acc += wr[d] * s_xs[d * TL + lt];
        s_xdbl[c * (TL + 1) + lt] = acc;
    }
    __syncthreads();

    long base = (long)bk * L_ + l0;

    // delta[lt][d] = softplus(bias[d] + sum_r Wdt[d][r] * xdbl[r][lt])
    for (int idx = tid; idx < TL * D_; idx += 256) {
        int lt = idx / D_, d = idx % D_;
        float acc = s_bias[d];
#pragma unroll
        for (int r = 0; r < R_; ++r)
            acc += s_wdt[r * D_ + d] * s_xdbl[r * (TL + 1) + lt];
        float sp = (acc > 20.f) ? acc : log1pf(__expf(acc));
        delta[(base + lt) * D_ + d] = sp;
    }
    // Bs/Cs: c = 6..21 -> Bs, 22..37 -> Cs
    for (int idx = tid; idx < TL * 2 * N_; idx += 256) {
        int lt = idx / (2 * N_), c2 = idx % (2 * N_);
        float v = s_xdbl[(R_ + c2) * (TL + 1) + lt];
        if (c2 < N_) Bsb[(base + lt) * N_ + c2] = v;
        else         Csb[(base + lt) * N_ + (c2 - N_)] = v;
    }
}

// ---------------------------------------------------------------------------
// Kernel B: selective scan. One wave (64 threads) per block; 4 (b,k,d)
// channels per wave, 16 lanes (=N states) per channel. Sequential over L.
// ---------------------------------------------------------------------------
__global__ __launch_bounds__(64) void scan_kernel(
    const float* __restrict__ x,      // (B,D,H,W)
    const float* __restrict__ A_logs, // (K*D, N)
    const float* __restrict__ Ds,     // (K*D)
    const float* __restrict__ delta,  // (B*K, L, 96)
    const float* __restrict__ Bsb,    // (B*K, L, 16)
    const float* __restrict__ Csb,    // (B*K, L, 16)
    float* __restrict__ ys)           // (B*K, L, 96)
{
    const int chans = D_ / 4;          // 24 blocks per bk
    int bid = blockIdx.x;              // B*K*chans = 384
    int bk = bid / chans;
    int d0 = (bid % chans) * 4;
    int b = bk / K_, k = bk % K_;
    int lane = threadIdx.x;
    int g = lane >> 4;                 // channel within wave
    int n = lane & 15;                 // state index
    int d = d0 + g;
    int kd = k * D_ + d;

    float A  = -__expf(A_logs[kd * N_ + n]);
    float Dv = Ds[kd];

    const float* dptr = delta + ((long)bk * L_) * D_ + d;
    const float* bptr = Bsb + (long)bk * L_ * N_ + n;
    const float* cptr = Csb + (long)bk * L_ * N_ + n;
    const float* xptr = x + ((long)b * D_ + d) * L_;
    float* yptr = ys + ((long)bk * L_) * D_ + d;

    float h = 0.f;
#pragma unroll 4
    for (int l = 0; l < L_; ++l) {
        float del = dptr[(long)l * D_];
        float u   = xptr[src_idx(k, l)];
        float Bt  = bptr[l * N_];
        float Ct  = cptr[l * N_];
        float dA  = __expf(del * A);
        h = h * dA + del * u * Bt;
        float yv = h * Ct;
        yv += __shfl_xor(yv, 1);
        yv += __shfl_xor(yv, 2);
        yv += __shfl_xor(yv, 4);
        yv += __shfl_xor(yv, 8);
        if (n == 0) yptr[(long)l * D_] = yv + Dv * u;
    }
}

// ---------------------------------------------------------------------------
// Kernel C: cross-merge + LayerNorm. One wave per (b,l) position.
// ---------------------------------------------------------------------------
__global__ __launch_bounds__(256) void merge_ln_kernel(
    const float* __restrict__ ys,   // (B*K, L, 96)
    const float* __restrict__ lnw,
    const float* __restrict__ lnb,
    float* __restrict__ out)        // (B, L, 96)
{
    int wid = (blockIdx.x * 256 + threadIdx.x) >> 6;  // 0 .. B*L-1
    int lane = threadIdx.x & 63;
    int b = wid / L_;
    int l = wid % L_;
    int lt = ((l & 63) << 6) | (l >> 6);              // transpose map

    long base0 = ((long)(b * K_ + 0) * L_ + l) * D_;
    long base2 = ((long)(b * K_ + 2) * L_ + (L_ - 1 - l)) * D_;
    long base1 = ((long)(b * K_ + 1) * L_ + lt) * D_;
    long base3 = ((long)(b * K_ + 3) * L_ + (L_ - 1 - lt)) * D_;

    int dA = lane;
    int dB = lane + 64;
    float v0 = ys[base0 + dA] + ys[base2 + dA] + ys[base1 + dA] + ys[base3 + dA];
    float v1 = 0.f;
    if (dB < D_)
        v1 = ys[base0 + dB] + ys[base2 + dB] + ys[base1 + dB] + ys[base3 + dB];

    float s  = v0 + v1;
    float s2 = v0 * v0 + v1 * v1;
#pragma unroll
    for (int m = 1; m < 64; m <<= 1) {
        s  += __shfl_xor(s, m);
        s2 += __shfl_xor(s2, m);
    }
    float mu  = s * (1.f / D_);
    float var = s2 * (1.f / D_) - mu * mu;
    float rstd = rsqrtf(var + 1e-5f);

    long obase = ((long)b * L_ + l) * D_;
    out[obase + dA] = (v0 - mu) * rstd * lnw[dA] + lnb[dA];
    if (dB < D_)
        out[obase + dB] = (v1 - mu) * rstd * lnw[dB] + lnb[dB];
}

extern "C" void kernel_launch(void* const* d_in, const int* in_sizes, int n_in,
                              void* d_out, int out_size, void* d_ws, size_t ws_size,
                              hipStream_t stream) {
    const float* x      = (const float*)d_in[0];  // (B,D,H,W)
    const float* xpw    = (const float*)d_in[1];  // (K,38,D)
    const float* wdt    = (const float*)d_in[2];  // (K,D,R)
    const float* bdt    = (const float*)d_in[3];  // (K,D)
    const float* A_logs = (const float*)d_in[4];  // (K*D,N)
    const float* Ds     = (const float*)d_in[5];  // (K*D)
    const float* lnw    = (const float*)d_in[6];  // (D)
    const float* lnb    = (const float*)d_in[7];  // (D)
    float* out = (float*)d_out;

    // Workspace layout (floats):
    float* ws = (float*)d_ws;
    const long n_delta = (long)B_ * K_ * L_ * D_;   // 6,291,456
    const long n_bc    = (long)B_ * K_ * L_ * N_;   // 1,048,576
    float* delta = ws;
    float* Bsb   = delta + n_delta;
    float* Csb   = Bsb + n_bc;
    float* ys    = Csb + n_bc;
    // total = 14,680,064 floats = ~58.7 MB

    proj_kernel<<<B_ * K_ * (L_ / 64), 256, 0, stream>>>(
        x, xpw, wdt, bdt, delta, Bsb, Csb);
    scan_kernel<<<B_ * K_ * (D_ / 4), 64, 0, stream>>>(
        x, A_logs, Ds, delta, Bsb, Csb, ys);
    merge_ln_kernel<<<(B_ * L_) / 4, 256, 0, stream>>>(
        ys, lnw, lnb, out);
}

// Round 2
// 323.807 us; speedup vs baseline: 5.7409x; 5.7409x over previous
//
#include <hip/hip_runtime.h>
#include <math.h>

#define B_ 4
#define D_ 96
#define H_ 64
#define W_ 64
#define L_ 4096
#define K_ 4
#define N_ 16
#define R_ 6
#define C_ 38   // R + 2N
#define S_ 32   // chunks per sequence
#define CL_ (L_ / S_)  // 128

// Flat index into x[b,d,:,:] (H*W) for cross-scan direction k at sequence pos l.
__device__ __forceinline__ int src_idx(int k, int l) {
    int m = (k >= 2) ? (L_ - 1 - l) : l;
    if (k & 1) {
        return ((m & 63) << 6) | (m >> 6);  // transpose map (H=W=64)
    }
    return m;
}

// ---------------------------------------------------------------------------
// Kernel A: projections. One block per (b, k, 64-wide l tile).
// ---------------------------------------------------------------------------
__global__ __launch_bounds__(256) void proj_kernel(
    const float* __restrict__ x,     // (B,D,H,W)
    const float* __restrict__ xpw,   // (K,38,96)
    const float* __restrict__ wdt,   // (K,96,6)
    const float* __restrict__ bdt,   // (K,96)
    float* __restrict__ delta,       // (B*K, L, 96)
    float* __restrict__ Bsb,         // (B*K, L, 16)
    float* __restrict__ Csb)         // (B*K, L, 16)
{
    const int TL = 64;
    const int tiles = L_ / TL;               // 64
    int bid = blockIdx.x;                    // B*K*tiles = 1024
    int bk = bid / tiles;
    int tile = bid % tiles;
    int b = bk / K_, k = bk % K_;
    int l0 = tile * TL;
    int tid = threadIdx.x;

    __shared__ float s_wp[C_ * D_];          // [c][d]
    __shared__ float s_wdt[R_ * D_];         // transposed [r][d]
    __shared__ float s_bias[D_];
    __shared__ float s_xs[D_ * TL];          // [d][lt]
    __shared__ float s_xdbl[C_ * (TL + 1)];  // [c][lt], padded

    for (int i = tid; i < C_ * D_; i += 256) s_wp[i] = xpw[k * C_ * D_ + i];
    for (int i = tid; i < R_ * D_; i += 256) {
        int r = i / D_, d = i % D_;
        s_wdt[i] = wdt[(k * D_ + d) * R_ + r];
    }
    if (tid < D_) s_bias[tid] = bdt[k * D_ + tid];
    for (int i = tid; i < D_ * TL; i += 256) {
        int d = i / TL, lt = i % TL;
        s_xs[i] = x[(b * D_ + d) * L_ + src_idx(k, l0 + lt)];
    }
    __syncthreads();

    for (int idx = tid; idx < C_ * TL; idx += 256) {
        int c = idx / TL, lt = idx % TL;
        const float* wr = &s_wp[c * D_];
        float acc = 0.f;
#pragma unroll 8
        for (int d = 0; d < D_; ++d) acc += wr[d] * s_xs[d * TL + lt];
        s_xdbl[c * (TL + 1) + lt] = acc;
    }
    __syncthreads();

    long base = (long)bk * L_ + l0;

    for (int idx = tid; idx < TL * D_; idx += 256) {
        int lt = idx / D_, d = idx % D_;
        float acc = s_bias[d];
#pragma unroll
        for (int r = 0; r < R_; ++r)
            acc += s_wdt[r * D_ + d] * s_xdbl[r * (TL + 1) + lt];
        float sp = (acc > 20.f) ? acc : log1pf(__expf(acc));
        delta[(base + lt) * D_ + d] = sp;
    }
    for (int idx = tid; idx < TL * 2 * N_; idx += 256) {
        int lt = idx / (2 * N_), c2 = idx % (2 * N_);
        float v = s_xdbl[(R_ + c2) * (TL + 1) + lt];
        if (c2 < N_) Bsb[(base + lt) * N_ + c2] = v;
        else         Csb[(base + lt) * N_ + (c2 - N_)] = v;
    }
}

// ---------------------------------------------------------------------------
// Chunked scan, pass 1: per-chunk local scan with h0=0; record (prod_a, h_fin).
// 256 threads = 4 waves; wave w handles channel-group q*4+w (4 d's x 16 n's).
// ---------------------------------------------------------------------------
__global__ __launch_bounds__(256) void scan_part1(
    const float* __restrict__ x,
    const float* __restrict__ A_logs,
    const float* __restrict__ delta,
    const float* __restrict__ Bsb,
    float* __restrict__ pAarr,   // [bk*D+d][n][S]
    float* __restrict__ hharr)   // [bk*D+d][n][S]  (h_fin, later h0 in-place)
{
    const int quads = (D_ / 4) / 4;          // 6
    int bid = blockIdx.x;                    // S * B*K*quads = 3072
    int j = bid / (B_ * K_ * quads);
    int rest = bid % (B_ * K_ * quads);
    int bk = rest / quads;
    int q = rest % quads;
    int tid = threadIdx.x;
    int w = tid >> 6, lane = tid & 63;
    int g = lane >> 4, n = lane & 15;
    int d = (q * 4 + w) * 4 + g;
    int b = bk / K_, k = bk % K_;
    int kd = k * D_ + d;

    float A = -__expf(A_logs[kd * N_ + n]);
    int l0 = j * CL_;
    const float* dptr = delta + ((long)bk * L_ + l0) * D_ + d;
    const float* bptr = Bsb + ((long)bk * L_ + l0) * N_ + n;
    const float* xptr = x + ((long)b * D_ + d) * L_;

    float h = 0.f, pA = 1.f;
#pragma unroll 4
    for (int t = 0; t < CL_; ++t) {
        float del = dptr[(long)t * D_];
        float u   = xptr[src_idx(k, l0 + t)];
        float Bt  = bptr[t * N_];
        float dA  = __expf(del * A);
        pA *= dA;
        h = h * dA + del * u * Bt;
    }
    long sbase = ((long)(bk * D_ + d) * N_ + n) * S_ + j;
    pAarr[sbase] = pA;
    hharr[sbase] = h;
}

// ---------------------------------------------------------------------------
// Chunked scan, pass 2: sequential combine over S chunk summaries (in-place:
// hharr[j] becomes the true h0 entering chunk j).
// ---------------------------------------------------------------------------
__global__ __launch_bounds__(256) void scan_combine(
    const float* __restrict__ pAarr,
    float* __restrict__ hharr)
{
    const int quads = (D_ / 4) / 4;          // 6
    int bid = blockIdx.x;                    // B*K*quads = 96
    int tid = threadIdx.x;
    int w = tid >> 6, lane = tid & 63;
    int bk = bid / quads, q = bid % quads;
    int g = lane >> 4, n = lane & 15;
    int d = (q * 4 + w) * 4 + g;
    long base = ((long)(bk * D_ + d) * N_ + n) * S_;
    float h = 0.f;
#pragma unroll
    for (int j = 0; j < S_; ++j) {
        float tmp = hharr[base + j];
        float pa  = pAarr[base + j];
        hharr[base + j] = h;
        h = tmp + pa * h;
    }
}

// ---------------------------------------------------------------------------
// Chunked scan, pass 3: re-run each chunk from its true h0, emit y.
// ---------------------------------------------------------------------------
__global__ __launch_bounds__(256) void scan_part2(
    const float* __restrict__ x,
    const float* __restrict__ A_logs,
    const float* __restrict__ Ds,
    const float* __restrict__ delta,
    const float* __restrict__ Bsb,
    const float* __restrict__ Csb,
    const float* __restrict__ hharr,
    float* __restrict__ ys)      // (B*K, L, 96)
{
    const int quads = (D_ / 4) / 4;
    int bid = blockIdx.x;
    int j = bid / (B_ * K_ * quads);
    int rest = bid % (B_ * K_ * quads);
    int bk = rest / quads;
    int q = rest % quads;
    int tid = threadIdx.x;
    int w = tid >> 6, lane = tid & 63;
    int g = lane >> 4, n = lane & 15;
    int d = (q * 4 + w) * 4 + g;
    int b = bk / K_, k = bk % K_;
    int kd = k * D_ + d;

    float A  = -__expf(A_logs[kd * N_ + n]);
    float Dv = Ds[kd];
    int l0 = j * CL_;
    const float* dptr = delta + ((long)bk * L_ + l0) * D_ + d;
    const float* bptr = Bsb + ((long)bk * L_ + l0) * N_ + n;
    const float* cptr = Csb + ((long)bk * L_ + l0) * N_ + n;
    const float* xptr = x + ((long)b * D_ + d) * L_;
    float* yptr = ys + ((long)bk * L_ + l0) * D_ + d;

    float h = hharr[((long)(bk * D_ + d) * N_ + n) * S_ + j];
#pragma unroll 4
    for (int t = 0; t < CL_; ++t) {
        float del = dptr[(long)t * D_];
        float u   = xptr[src_idx(k, l0 + t)];
        float Bt  = bptr[t * N_];
        float Ct  = cptr[t * N_];
        float dA  = __expf(del * A);
        h = h * dA + del * u * Bt;
        float yv = h * Ct;
        yv += __shfl_xor(yv, 1);
        yv += __shfl_xor(yv, 2);
        yv += __shfl_xor(yv, 4);
        yv += __shfl_xor(yv, 8);
        if (n == 0) yptr[(long)t * D_] = yv + Dv * u;
    }
}

// ---------------------------------------------------------------------------
// Serial fallback scan (used only if ws_size is too small for summaries).
// ---------------------------------------------------------------------------
__global__ __launch_bounds__(64) void scan_serial(
    const float* __restrict__ x,
    const float* __restrict__ A_logs,
    const float* __restrict__ Ds,
    const float* __restrict__ delta,
    const float* __restrict__ Bsb,
    const float* __restrict__ Csb,
    float* __restrict__ ys)
{
    const int chans = D_ / 4;
    int bid = blockIdx.x;
    int bk = bid / chans;
    int d0 = (bid % chans) * 4;
    int b = bk / K_, k = bk % K_;
    int lane = threadIdx.x;
    int g = lane >> 4, n = lane & 15;
    int d = d0 + g;
    int kd = k * D_ + d;

    float A  = -__expf(A_logs[kd * N_ + n]);
    float Dv = Ds[kd];
    const float* dptr = delta + ((long)bk * L_) * D_ + d;
    const float* bptr = Bsb + (long)bk * L_ * N_ + n;
    const float* cptr = Csb + (long)bk * L_ * N_ + n;
    const float* xptr = x + ((long)b * D_ + d) * L_;
    float* yptr = ys + ((long)bk * L_) * D_ + d;

    float h = 0.f;
#pragma unroll 4
    for (int l = 0; l < L_; ++l) {
        float del = dptr[(long)l * D_];
        float u   = xptr[src_idx(k, l)];
        float Bt  = bptr[l * N_];
        float Ct  = cptr[l * N_];
        float dA  = __expf(del * A);
        h = h * dA + del * u * Bt;
        float yv = h * Ct;
        yv += __shfl_xor(yv, 1);
        yv += __shfl_xor(yv, 2);
        yv += __shfl_xor(yv, 4);
        yv += __shfl_xor(yv, 8);
        if (n == 0) yptr[(long)l * D_] = yv + Dv * u;
    }
}

// ---------------------------------------------------------------------------
// Kernel C: cross-merge + LayerNorm. One wave per (b,l) position.
// ---------------------------------------------------------------------------
__global__ __launch_bounds__(256) void merge_ln_kernel(
    const float* __restrict__ ys,
    const float* __restrict__ lnw,
    const float* __restrict__ lnb,
    float* __restrict__ out)
{
    int wid = (blockIdx.x * 256 + threadIdx.x) >> 6;
    int lane = threadIdx.x & 63;
    int b = wid / L_;
    int l = wid % L_;
    int lt = ((l & 63) << 6) | (l >> 6);

    long base0 = ((long)(b * K_ + 0) * L_ + l) * D_;
    long base2 = ((long)(b * K_ + 2) * L_ + (L_ - 1 - l)) * D_;
    long base1 = ((long)(b * K_ + 1) * L_ + lt) * D_;
    long base3 = ((long)(b * K_ + 3) * L_ + (L_ - 1 - lt)) * D_;

    int dA = lane;
    int dB = lane + 64;
    float v0 = ys[base0 + dA] + ys[base2 + dA] + ys[base1 + dA] + ys[base3 + dA];
    float v1 = 0.f;
    if (dB < D_)
        v1 = ys[base0 + dB] + ys[base2 + dB] + ys[base1 + dB] + ys[base3 + dB];

    float s  = v0 + v1;
    float s2 = v0 * v0 + v1 * v1;
#pragma unroll
    for (int m = 1; m < 64; m <<= 1) {
        s  += __shfl_xor(s, m);
        s2 += __shfl_xor(s2, m);
    }
    float mu  = s * (1.f / D_);
    float var = s2 * (1.f / D_) - mu * mu;
    float rstd = rsqrtf(var + 1e-5f);

    long obase = ((long)b * L_ + l) * D_;
    out[obase + dA] = (v0 - mu) * rstd * lnw[dA] + lnb[dA];
    if (dB < D_)
        out[obase + dB] = (v1 - mu) * rstd * lnw[dB] + lnb[dB];
}

extern "C" void kernel_launch(void* const* d_in, const int* in_sizes, int n_in,
                              void* d_out, int out_size, void* d_ws, size_t ws_size,
                              hipStream_t stream) {
    const float* x      = (const float*)d_in[0];
    const float* xpw    = (const float*)d_in[1];
    const float* wdt    = (const float*)d_in[2];
    const float* bdt    = (const float*)d_in[3];
    const float* A_logs = (const float*)d_in[4];
    const float* Ds     = (const float*)d_in[5];
    const float* lnw    = (const float*)d_in[6];
    const float* lnb    = (const float*)d_in[7];
    float* out = (float*)d_out;

    float* ws = (float*)d_ws;
    const long n_delta = (long)B_ * K_ * L_ * D_;     // 6,291,456
    const long n_bc    = (long)B_ * K_ * L_ * N_;     // 1,048,576
    const long n_sum   = (long)B_ * K_ * D_ * N_ * S_;// 786,432
    float* delta = ws;
    float* Bsb   = delta + n_delta;
    float* Csb   = Bsb + n_bc;
    float* ys    = Csb + n_bc;
    float* pAarr = ys + n_delta;
    float* hharr = pAarr + n_sum;
    size_t need = (size_t)(n_delta * 2 + n_bc * 2 + n_sum * 2) * sizeof(float); // ~65 MB

    proj_kernel<<<B_ * K_ * (L_ / 64), 256, 0, stream>>>(
        x, xpw, wdt, bdt, delta, Bsb, Csb);

    const int quads = (D_ / 4) / 4;  // 6
    if (ws_size >= need) {
        scan_part1<<<S_ * B_ * K_ * quads, 256, 0, stream>>>(
            x, A_logs, delta, Bsb, pAarr, hharr);
        scan_combine<<<B_ * K_ * quads, 256, 0, stream>>>(pAarr, hharr);
        scan_part2<<<S_ * B_ * K_ * quads, 256, 0, stream>>>(
            x, A_logs, Ds, delta, Bsb, Csb, hharr, ys);
    } else {
        scan_serial<<<B_ * K_ * (D_ / 4), 64, 0, stream>>>(
            x, A_logs, Ds, delta, Bsb, Csb, ys);
    }

    merge_ln_kernel<<<(B_ * L_) / 4, 256, 0, stream>>>(
        ys, lnw, lnb, out);
}

// Round 3
// 297.096 us; speedup vs baseline: 6.2570x; 1.0899x over previous
//
#include <hip/hip_runtime.h>
#include <math.h>

#define B_ 4
#define D_ 96
#define H_ 64
#define W_ 64
#define L_ 4096
#define K_ 4
#define N_ 16
#define R_ 6
#define C_ 38   // R + 2N
#define S_ 32   // chunks per sequence
#define CL_ (L_ / S_)  // 128
#define CH_ (B_ * K_ * D_ * N_)  // 24576 scan channels

// Flat index into x[b,d,:,:] (H*W) for cross-scan direction k at sequence pos l.
__device__ __forceinline__ int src_idx(int k, int l) {
    int m = (k >= 2) ? (L_ - 1 - l) : l;
    if (k & 1) {
        return ((m & 63) << 6) | (m >> 6);  // transpose map (H=W=64)
    }
    return m;
}

// ---------------------------------------------------------------------------
// Kernel A: projections + xs materialization. One block per (b,k, 64-l tile).
// Outputs delta[bk][l][96], xs_t[bk][l][96], Bs[bk][l][16], Cs[bk][l][16].
// ---------------------------------------------------------------------------
__global__ __launch_bounds__(256) void proj_kernel(
    const float* __restrict__ x,     // (B,D,H,W)
    const float* __restrict__ xpw,   // (K,38,96)
    const float* __restrict__ wdt,   // (K,96,6)
    const float* __restrict__ bdt,   // (K,96)
    float* __restrict__ delta,
    float* __restrict__ xs_t,
    float* __restrict__ Bsb,
    float* __restrict__ Csb)
{
    const int TL = 64;
    const int tiles = L_ / TL;               // 64
    int bid = blockIdx.x;                    // B*K*tiles = 1024
    int bk = bid / tiles;
    int tile = bid % tiles;
    int b = bk / K_, k = bk % K_;
    int l0 = tile * TL;
    int tid = threadIdx.x;

    __shared__ float s_wp[C_ * D_];            // [c][d]
    __shared__ float s_wdt[R_ * D_];           // transposed [r][d]
    __shared__ float s_bias[D_];
    __shared__ float s_xs[D_ * (TL + 1)];      // [d][lt], padded (+1 breaks conflicts)
    __shared__ float s_xdbl[C_ * (TL + 1)];    // [c][lt], padded

    for (int i = tid; i < C_ * D_; i += 256) s_wp[i] = xpw[k * C_ * D_ + i];
    for (int i = tid; i < R_ * D_; i += 256) {
        int r = i / D_, d = i % D_;
        s_wdt[i] = wdt[(k * D_ + d) * R_ + r];
    }
    if (tid < D_) s_bias[tid] = bdt[k * D_ + tid];
    for (int i = tid; i < D_ * TL; i += 256) {
        int d = i / TL, lt = i % TL;
        s_xs[d * (TL + 1) + lt] = x[(b * D_ + d) * L_ + src_idx(k, l0 + lt)];
    }
    __syncthreads();

    for (int idx = tid; idx < C_ * TL; idx += 256) {
        int c = idx / TL, lt = idx % TL;
        const float* wr = &s_wp[c * D_];
        float acc = 0.f;
#pragma unroll 8
        for (int d = 0; d < D_; ++d) acc += wr[d] * s_xs[d * (TL + 1) + lt];
        s_xdbl[c * (TL + 1) + lt] = acc;
    }
    __syncthreads();

    long base = (long)bk * L_ + l0;

    // delta + xs_t, coalesced over d
    for (int idx = tid; idx < TL * D_; idx += 256) {
        int lt = idx / D_, d = idx % D_;
        float acc = s_bias[d];
#pragma unroll
        for (int r = 0; r < R_; ++r)
            acc += s_wdt[r * D_ + d] * s_xdbl[r * (TL + 1) + lt];
        float sp = (acc > 20.f) ? acc : log1pf(__expf(acc));
        delta[(base + lt) * D_ + d] = sp;
        xs_t[(base + lt) * D_ + d] = s_xs[d * (TL + 1) + lt];
    }
    for (int idx = tid; idx < TL * 2 * N_; idx += 256) {
        int lt = idx / (2 * N_), c2 = idx % (2 * N_);
        float v = s_xdbl[(R_ + c2) * (TL + 1) + lt];
        if (c2 < N_) Bsb[(base + lt) * N_ + c2] = v;
        else         Csb[(base + lt) * N_ + (c2 - N_)] = v;
    }
}

// ---------------------------------------------------------------------------
// Pass 1: per-chunk local scan (h0=0), LDS-staged tiles, record (prod_a, h_fin).
// Block = 256 threads = 4 waves = 16 d's; grid = S * B*K * (D/16).
// Summary layout: [j][ (bk*96+d)*16+n ]  -> coalesced everywhere.
// ---------------------------------------------------------------------------
__global__ __launch_bounds__(256) void scan_part1(
    const float* __restrict__ A_logs,
    const float* __restrict__ delta,
    const float* __restrict__ xs_t,
    const float* __restrict__ Bsb,
    float* __restrict__ pAarr,   // [S][CH]
    float* __restrict__ hharr)   // [S][CH]
{
    const int grp = D_ / 16;                 // 6
    int bid = blockIdx.x;                    // S*B*K*grp = 3072
    int j = bid / (B_ * K_ * grp);
    int rest = bid % (B_ * K_ * grp);
    int bk = rest / grp;
    int q = rest % grp;
    int d0 = q * 16;
    int l0 = j * CL_;
    int tid = threadIdx.x;

    __shared__ __align__(16) float s_del[CL_ * 16];
    __shared__ __align__(16) float s_u[CL_ * 16];
    __shared__ __align__(16) float s_B[CL_ * 16];

    const float* dbase = delta + ((long)bk * L_ + l0) * D_ + d0;
    const float* ubase = xs_t + ((long)bk * L_ + l0) * D_ + d0;
    const float* bbase = Bsb + ((long)bk * L_ + l0) * N_;
    for (int i = tid; i < CL_ * 4; i += 256) {
        int t = i >> 2, c = i & 3;
        ((float4*)s_del)[i] = *(const float4*)(dbase + (long)t * D_ + c * 4);
        ((float4*)s_u)[i]   = *(const float4*)(ubase + (long)t * D_ + c * 4);
        ((float4*)s_B)[i]   = *(const float4*)(bbase + t * N_ + c * 4);
    }
    __syncthreads();

    int w = tid >> 6, lane = tid & 63;
    int g = lane >> 4, n = lane & 15;
    int dl = w * 4 + g;
    int d = d0 + dl;
    int kd = (bk % K_) * D_ + d;
    float A = -__expf(A_logs[kd * N_ + n]);

    float h = 0.f, pA = 1.f;
#pragma unroll 8
    for (int t = 0; t < CL_; ++t) {
        float del = s_del[t * 16 + dl];
        float u   = s_u[t * 16 + dl];
        float Bt  = s_B[t * 16 + n];
        float dA  = __expf(del * A);
        pA *= dA;
        h = h * dA + del * u * Bt;
    }
    long sbase = (long)j * CH_ + (long)(bk * D_ + d) * N_ + n;
    pAarr[sbase] = pA;
    hharr[sbase] = h;
}

// ---------------------------------------------------------------------------
// Pass 2: sequential combine over S chunk summaries (in-place: hharr[j] becomes
// the true h0 entering chunk j). One thread per channel; coalesced per j.
// ---------------------------------------------------------------------------
__global__ __launch_bounds__(256) void scan_combine(
    const float* __restrict__ pAarr,
    float* __restrict__ hharr)
{
    int c = blockIdx.x * 256 + threadIdx.x;  // 0..CH-1
    float h = 0.f;
#pragma unroll
    for (int j = 0; j < S_; ++j) {
        long idx = (long)j * CH_ + c;
        float tmp = hharr[idx];
        float pa  = pAarr[idx];
        hharr[idx] = h;
        h = tmp + pa * h;
    }
}

// ---------------------------------------------------------------------------
// Pass 3: re-run each chunk from its true h0, emit y (staged through LDS).
// ---------------------------------------------------------------------------
__global__ __launch_bounds__(256) void scan_part2(
    const float* __restrict__ A_logs,
    const float* __restrict__ Ds,
    const float* __restrict__ delta,
    const float* __restrict__ xs_t,
    const float* __restrict__ Bsb,
    const float* __restrict__ Csb,
    const float* __restrict__ hharr,
    float* __restrict__ ys)      // (B*K, L, 96)
{
    const int grp = D_ / 16;
    int bid = blockIdx.x;
    int j = bid / (B_ * K_ * grp);
    int rest = bid % (B_ * K_ * grp);
    int bk = rest / grp;
    int q = rest % grp;
    int d0 = q * 16;
    int l0 = j * CL_;
    int tid = threadIdx.x;

    __shared__ __align__(16) float s_del[CL_ * 16];  // becomes y tile in-place
    __shared__ __align__(16) float s_u[CL_ * 16];
    __shared__ __align__(16) float s_B[CL_ * 16];
    __shared__ __align__(16) float s_C[CL_ * 16];

    const float* dbase = delta + ((long)bk * L_ + l0) * D_ + d0;
    const float* ubase = xs_t + ((long)bk * L_ + l0) * D_ + d0;
    const float* bbase = Bsb + ((long)bk * L_ + l0) * N_;
    const float* cbase = Csb + ((long)bk * L_ + l0) * N_;
    for (int i = tid; i < CL_ * 4; i += 256) {
        int t = i >> 2, c = i & 3;
        ((float4*)s_del)[i] = *(const float4*)(dbase + (long)t * D_ + c * 4);
        ((float4*)s_u)[i]   = *(const float4*)(ubase + (long)t * D_ + c * 4);
        ((float4*)s_B)[i]   = *(const float4*)(bbase + t * N_ + c * 4);
        ((float4*)s_C)[i]   = *(const float4*)(cbase + t * N_ + c * 4);
    }
    __syncthreads();

    int w = tid >> 6, lane = tid & 63;
    int g = lane >> 4, n = lane & 15;
    int dl = w * 4 + g;
    int d = d0 + dl;
    int kd = (bk % K_) * D_ + d;
    float A  = -__expf(A_logs[kd * N_ + n]);
    float Dv = Ds[kd];

    float h = hharr[(long)j * CH_ + (long)(bk * D_ + d) * N_ + n];
#pragma unroll 8
    for (int t = 0; t < CL_; ++t) {
        float del = s_del[t * 16 + dl];
        float u   = s_u[t * 16 + dl];
        float Bt  = s_B[t * 16 + n];
        float Ct  = s_C[t * 16 + n];
        float dA  = __expf(del * A);
        h = h * dA + del * u * Bt;
        float yv = h * Ct;
        yv += __shfl_xor(yv, 1);
        yv += __shfl_xor(yv, 2);
        yv += __shfl_xor(yv, 4);
        yv += __shfl_xor(yv, 8);
        // each wave owns columns dl = w*4..w*4+3 of s_del -> safe in-place
        if (n == 0) s_del[t * 16 + dl] = yv + Dv * u;
    }
    __syncthreads();

    float* ybase = ys + ((long)bk * L_ + l0) * D_ + d0;
    for (int i = tid; i < CL_ * 4; i += 256) {
        int t = i >> 2, c = i & 3;
        *(float4*)(ybase + (long)t * D_ + c * 4) = ((float4*)s_del)[i];
    }
}

// ---------------------------------------------------------------------------
// Serial fallback scan (only if ws_size too small).
// ---------------------------------------------------------------------------
__global__ __launch_bounds__(64) void scan_serial(
    const float* __restrict__ x,
    const float* __restrict__ A_logs,
    const float* __restrict__ Ds,
    const float* __restrict__ delta,
    const float* __restrict__ Bsb,
    const float* __restrict__ Csb,
    float* __restrict__ ys)
{
    const int chans = D_ / 4;
    int bid = blockIdx.x;
    int bk = bid / chans;
    int d0 = (bid % chans) * 4;
    int b = bk / K_, k = bk % K_;
    int lane = threadIdx.x;
    int g = lane >> 4, n = lane & 15;
    int d = d0 + g;
    int kd = k * D_ + d;

    float A  = -__expf(A_logs[kd * N_ + n]);
    float Dv = Ds[kd];
    const float* dptr = delta + ((long)bk * L_) * D_ + d;
    const float* bptr = Bsb + (long)bk * L_ * N_ + n;
    const float* cptr = Csb + (long)bk * L_ * N_ + n;
    const float* xptr = x + ((long)b * D_ + d) * L_;
    float* yptr = ys + ((long)bk * L_) * D_ + d;

    float h = 0.f;
#pragma unroll 4
    for (int l = 0; l < L_; ++l) {
        float del = dptr[(long)l * D_];
        float u   = xptr[src_idx(k, l)];
        float Bt  = bptr[l * N_];
        float Ct  = cptr[l * N_];
        float dA  = __expf(del * A);
        h = h * dA + del * u * Bt;
        float yv = h * Ct;
        yv += __shfl_xor(yv, 1);
        yv += __shfl_xor(yv, 2);
        yv += __shfl_xor(yv, 4);
        yv += __shfl_xor(yv, 8);
        if (n == 0) yptr[(long)l * D_] = yv + Dv * u;
    }
}

// ---------------------------------------------------------------------------
// Kernel C: cross-merge + LayerNorm. One wave per (b,l) position.
// ---------------------------------------------------------------------------
__global__ __launch_bounds__(256) void merge_ln_kernel(
    const float* __restrict__ ys,
    const float* __restrict__ lnw,
    const float* __restrict__ lnb,
    float* __restrict__ out)
{
    int wid = (blockIdx.x * 256 + threadIdx.x) >> 6;
    int lane = threadIdx.x & 63;
    int b = wid / L_;
    int l = wid % L_;
    int lt = ((l & 63) << 6) | (l >> 6);

    long base0 = ((long)(b * K_ + 0) * L_ + l) * D_;
    long base2 = ((long)(b * K_ + 2) * L_ + (L_ - 1 - l)) * D_;
    long base1 = ((long)(b * K_ + 1) * L_ + lt) * D_;
    long base3 = ((long)(b * K_ + 3) * L_ + (L_ - 1 - lt)) * D_;

    int dA = lane;
    int dB = lane + 64;
    float v0 = ys[base0 + dA] + ys[base2 + dA] + ys[base1 + dA] + ys[base3 + dA];
    float v1 = 0.f;
    if (dB < D_)
        v1 = ys[base0 + dB] + ys[base2 + dB] + ys[base1 + dB] + ys[base3 + dB];

    float s  = v0 + v1;
    float s2 = v0 * v0 + v1 * v1;
#pragma unroll
    for (int m = 1; m < 64; m <<= 1) {
        s  += __shfl_xor(s, m);
        s2 += __shfl_xor(s2, m);
    }
    float mu  = s * (1.f / D_);
    float var = s2 * (1.f / D_) - mu * mu;
    float rstd = rsqrtf(var + 1e-5f);

    long obase = ((long)b * L_ + l) * D_;
    out[obase + dA] = (v0 - mu) * rstd * lnw[dA] + lnb[dA];
    if (dB < D_)
        out[obase + dB] = (v1 - mu) * rstd * lnw[dB] + lnb[dB];
}

extern "C" void kernel_launch(void* const* d_in, const int* in_sizes, int n_in,
                              void* d_out, int out_size, void* d_ws, size_t ws_size,
                              hipStream_t stream) {
    const float* x      = (const float*)d_in[0];
    const float* xpw    = (const float*)d_in[1];
    const float* wdt    = (const float*)d_in[2];
    const float* bdt    = (const float*)d_in[3];
    const float* A_logs = (const float*)d_in[4];
    const float* Ds     = (const float*)d_in[5];
    const float* lnw    = (const float*)d_in[6];
    const float* lnb    = (const float*)d_in[7];
    float* out = (float*)d_out;

    float* ws = (float*)d_ws;
    const long n_delta = (long)B_ * K_ * L_ * D_;     // 6,291,456
    const long n_bc    = (long)B_ * K_ * L_ * N_;     // 1,048,576
    const long n_sum   = (long)S_ * CH_;              // 786,432
    float* delta = ws;
    float* xs_t  = delta + n_delta;
    float* Bsb   = xs_t + n_delta;
    float* Csb   = Bsb + n_bc;
    float* ys    = Csb + n_bc;
    float* pAarr = ys + n_delta;
    float* hharr = pAarr + n_sum;
    size_t need = (size_t)(n_delta * 3 + n_bc * 2 + n_sum * 2) * sizeof(float); // ~90 MB

    const int grp = D_ / 16;  // 6

    if (ws_size >= need) {
        proj_kernel<<<B_ * K_ * (L_ / 64), 256, 0, stream>>>(
            x, xpw, wdt, bdt, delta, xs_t, Bsb, Csb);
        scan_part1<<<S_ * B_ * K_ * grp, 256, 0, stream>>>(
            A_logs, delta, xs_t, Bsb, pAarr, hharr);
        scan_combine<<<CH_ / 256, 256, 0, stream>>>(pAarr, hharr);
        scan_part2<<<S_ * B_ * K_ * grp, 256, 0, stream>>>(
            A_logs, Ds, delta, xs_t, Bsb, Csb, hharr, ys);
        merge_ln_kernel<<<(B_ * L_) / 4, 256, 0, stream>>>(ys, lnw, lnb, out);
    } else {
        // Fallback: smaller footprint (~59 MB), serial scan.
        float* ys2 = Csb + n_bc;
        proj_kernel<<<B_ * K_ * (L_ / 64), 256, 0, stream>>>(
            x, xpw, wdt, bdt, delta, xs_t, Bsb, Csb);  // xs_t aliases fine (within need)
        scan_serial<<<B_ * K_ * (D_ / 4), 64, 0, stream>>>(
            x, A_logs, Ds, delta, Bsb, Csb, ys2);
        merge_ln_kernel<<<(B_ * L_) / 4, 256, 0, stream>>>(ys2, lnw, lnb, out);
    }
}

// Round 4
// 216.650 us; speedup vs baseline: 8.5804x; 1.3713x over previous
//
#include <hip/hip_runtime.h>
#include <math.h>

#define B_ 4
#define D_ 96
#define H_ 64
#define W_ 64
#define L_ 4096
#define K_ 4
#define N_ 16
#define R_ 6
#define C_ 38   // R + 2N
#define S_ 64   // chunks per sequence
#define CL_ (L_ / S_)  // 64
#define CH_ (B_ * K_ * D_ * N_)  // 24576 scan channels

// Flat index into x[b,d,:,:] (H*W) for cross-scan direction k at sequence pos l.
__device__ __forceinline__ int src_idx(int k, int l) {
    int m = (k >= 2) ? (L_ - 1 - l) : l;
    if (k & 1) {
        return ((m & 63) << 6) | (m >> 6);  // transpose map (H=W=64)
    }
    return m;
}

// ---------------------------------------------------------------------------
// Kernel A: projections + xs materialization. One block per (b,k, 64-l tile).
// ---------------------------------------------------------------------------
__global__ __launch_bounds__(256) void proj_kernel(
    const float* __restrict__ x,     // (B,D,H,W)
    const float* __restrict__ xpw,   // (K,38,96)
    const float* __restrict__ wdt,   // (K,96,6)
    const float* __restrict__ bdt,   // (K,96)
    float* __restrict__ delta,
    float* __restrict__ xs_t,
    float* __restrict__ Bsb,
    float* __restrict__ Csb)
{
    const int TL = 64;
    const int tiles = L_ / TL;               // 64
    int bid = blockIdx.x;                    // B*K*tiles = 1024
    int bk = bid / tiles;
    int tile = bid % tiles;
    int b = bk / K_, k = bk % K_;
    int l0 = tile * TL;
    int tid = threadIdx.x;

    __shared__ float s_wp[C_ * D_];            // [c][d]
    __shared__ float s_wdt[R_ * D_];           // transposed [r][d]
    __shared__ float s_bias[D_];
    __shared__ float s_xs[D_ * (TL + 1)];      // [d][lt], padded
    __shared__ float s_xdbl[C_ * (TL + 1)];    // [c][lt], padded

    for (int i = tid; i < C_ * D_; i += 256) s_wp[i] = xpw[k * C_ * D_ + i];
    for (int i = tid; i < R_ * D_; i += 256) {
        int r = i / D_, d = i % D_;
        s_wdt[i] = wdt[(k * D_ + d) * R_ + r];
    }
    if (tid < D_) s_bias[tid] = bdt[k * D_ + tid];
    for (int i = tid; i < D_ * TL; i += 256) {
        int d = i / TL, lt = i % TL;
        s_xs[d * (TL + 1) + lt] = x[(b * D_ + d) * L_ + src_idx(k, l0 + lt)];
    }
    __syncthreads();

    for (int idx = tid; idx < C_ * TL; idx += 256) {
        int c = idx / TL, lt = idx % TL;
        const float* wr = &s_wp[c * D_];
        float acc = 0.f;
#pragma unroll 8
        for (int d = 0; d < D_; ++d) acc += wr[d] * s_xs[d * (TL + 1) + lt];
        s_xdbl[c * (TL + 1) + lt] = acc;
    }
    __syncthreads();

    long base = (long)bk * L_ + l0;

    for (int idx = tid; idx < TL * D_; idx += 256) {
        int lt = idx / D_, d = idx % D_;
        float acc = s_bias[d];
#pragma unroll
        for (int r = 0; r < R_; ++r)
            acc += s_wdt[r * D_ + d] * s_xdbl[r * (TL + 1) + lt];
        float sp = (acc > 20.f) ? acc : log1pf(__expf(acc));
        delta[(base + lt) * D_ + d] = sp;
        xs_t[(base + lt) * D_ + d] = s_xs[d * (TL + 1) + lt];
    }
    for (int idx = tid; idx < TL * 2 * N_; idx += 256) {
        int lt = idx / (2 * N_), c2 = idx % (2 * N_);
        float v = s_xdbl[(R_ + c2) * (TL + 1) + lt];
        if (c2 < N_) Bsb[(base + lt) * N_ + c2] = v;
        else         Csb[(base + lt) * N_ + (c2 - N_)] = v;
    }
}

// ---------------------------------------------------------------------------
// Pass 1: per-chunk local scan (h0=0), register-resident h[8]/pA[8].
// Block = 192 threads = one (bk, j); thread = (d, n-half). No LDS.
// Summary layout: [j][ (bk*96+d)*16+n ]  -> coalesced float4 stores.
// ---------------------------------------------------------------------------
__global__ __launch_bounds__(192) void scan_part1(
    const float* __restrict__ A_logs,
    const float* __restrict__ delta,
    const float* __restrict__ xs_t,
    const float* __restrict__ Bsb,
    float* __restrict__ pAarr,   // [S][CH]
    float* __restrict__ hharr)   // [S][CH]
{
    int bid = blockIdx.x;           // B*K*S = 1024
    int bk = bid / S_;
    int j = bid % S_;
    int tid = threadIdx.x;
    int dd = tid >> 1;              // 0..95
    int half = tid & 1;
    int n0 = half * 8;
    int k = bk % K_;
    int kd = k * D_ + dd;
    int l0 = j * CL_;

    float Av[8];
    {
        const float4* ap = (const float4*)(A_logs + kd * N_ + n0);
        float4 a0 = ap[0], a1 = ap[1];
        Av[0] = -__expf(a0.x); Av[1] = -__expf(a0.y);
        Av[2] = -__expf(a0.z); Av[3] = -__expf(a0.w);
        Av[4] = -__expf(a1.x); Av[5] = -__expf(a1.y);
        Av[6] = -__expf(a1.z); Av[7] = -__expf(a1.w);
    }

    const float* dp = delta + ((long)bk * L_ + l0) * D_ + dd;
    const float* up = xs_t + ((long)bk * L_ + l0) * D_ + dd;
    const float* bp = Bsb + ((long)bk * L_ + l0) * N_ + n0;

    float h[8], pA[8];
#pragma unroll
    for (int i = 0; i < 8; ++i) { h[i] = 0.f; pA[i] = 1.f; }

#pragma unroll 4
    for (int t = 0; t < CL_; ++t) {
        float del = dp[t * D_];
        float u   = up[t * D_];
        float4 b0 = *(const float4*)(bp + t * N_);
        float4 b1 = *(const float4*)(bp + t * N_ + 4);
        float Bv[8] = {b0.x, b0.y, b0.z, b0.w, b1.x, b1.y, b1.z, b1.w};
        float delu = del * u;
#pragma unroll
        for (int i = 0; i < 8; ++i) {
            float dA = __expf(del * Av[i]);
            pA[i] *= dA;
            h[i] = h[i] * dA + delu * Bv[i];
        }
    }

    long sbase = (long)j * CH_ + (long)(bk * D_ + dd) * N_ + n0;
    *(float4*)(pAarr + sbase)     = make_float4(pA[0], pA[1], pA[2], pA[3]);
    *(float4*)(pAarr + sbase + 4) = make_float4(pA[4], pA[5], pA[6], pA[7]);
    *(float4*)(hharr + sbase)     = make_float4(h[0], h[1], h[2], h[3]);
    *(float4*)(hharr + sbase + 4) = make_float4(h[4], h[5], h[6], h[7]);
}

// ---------------------------------------------------------------------------
// Pass 2: sequential combine over S chunk summaries (in-place).
// ---------------------------------------------------------------------------
__global__ __launch_bounds__(256) void scan_combine(
    const float* __restrict__ pAarr,
    float* __restrict__ hharr)
{
    int c = blockIdx.x * 256 + threadIdx.x;  // 0..CH-1
    float h = 0.f;
#pragma unroll 8
    for (int j = 0; j < S_; ++j) {
        long idx = (long)j * CH_ + c;
        float tmp = hharr[idx];
        float pa  = pAarr[idx];
        hharr[idx] = h;
        h = tmp + pa * h;
    }
}

// ---------------------------------------------------------------------------
// Pass 3: re-run each chunk from its true h0, emit y. Register h[8], no LDS.
// ---------------------------------------------------------------------------
__global__ __launch_bounds__(192) void scan_part2(
    const float* __restrict__ A_logs,
    const float* __restrict__ Ds,
    const float* __restrict__ delta,
    const float* __restrict__ xs_t,
    const float* __restrict__ Bsb,
    const float* __restrict__ Csb,
    const float* __restrict__ hharr,
    float* __restrict__ ys)      // (B*K, L, 96)
{
    int bid = blockIdx.x;
    int bk = bid / S_;
    int j = bid % S_;
    int tid = threadIdx.x;
    int dd = tid >> 1;
    int half = tid & 1;
    int n0 = half * 8;
    int k = bk % K_;
    int kd = k * D_ + dd;
    int l0 = j * CL_;

    float Av[8];
    {
        const float4* ap = (const float4*)(A_logs + kd * N_ + n0);
        float4 a0 = ap[0], a1 = ap[1];
        Av[0] = -__expf(a0.x); Av[1] = -__expf(a0.y);
        Av[2] = -__expf(a0.z); Av[3] = -__expf(a0.w);
        Av[4] = -__expf(a1.x); Av[5] = -__expf(a1.y);
        Av[6] = -__expf(a1.z); Av[7] = -__expf(a1.w);
    }
    float Dv = Ds[kd];

    const float* dp = delta + ((long)bk * L_ + l0) * D_ + dd;
    const float* up = xs_t + ((long)bk * L_ + l0) * D_ + dd;
    const float* bp = Bsb + ((long)bk * L_ + l0) * N_ + n0;
    const float* cp = Csb + ((long)bk * L_ + l0) * N_ + n0;
    float* yp = ys + ((long)bk * L_ + l0) * D_ + dd;

    float h[8];
    {
        long sbase = (long)j * CH_ + (long)(bk * D_ + dd) * N_ + n0;
        float4 h0 = *(const float4*)(hharr + sbase);
        float4 h1 = *(const float4*)(hharr + sbase + 4);
        h[0] = h0.x; h[1] = h0.y; h[2] = h0.z; h[3] = h0.w;
        h[4] = h1.x; h[5] = h1.y; h[6] = h1.z; h[7] = h1.w;
    }

#pragma unroll 4
    for (int t = 0; t < CL_; ++t) {
        float del = dp[t * D_];
        float u   = up[t * D_];
        float4 b0 = *(const float4*)(bp + t * N_);
        float4 b1 = *(const float4*)(bp + t * N_ + 4);
        float4 c0 = *(const float4*)(cp + t * N_);
        float4 c1 = *(const float4*)(cp + t * N_ + 4);
        float Bv[8] = {b0.x, b0.y, b0.z, b0.w, b1.x, b1.y, b1.z, b1.w};
        float Cv[8] = {c0.x, c0.y, c0.z, c0.w, c1.x, c1.y, c1.z, c1.w};
        float delu = del * u;
        float y = 0.f;
#pragma unroll
        for (int i = 0; i < 8; ++i) {
            float dA = __expf(del * Av[i]);
            h[i] = h[i] * dA + delu * Bv[i];
            y += h[i] * Cv[i];
        }
        y += __shfl_xor(y, 1);
        if (half == 0) yp[t * D_] = y + Dv * u;
    }
}

// ---------------------------------------------------------------------------
// Serial fallback scan (only if ws_size too small).
// ---------------------------------------------------------------------------
__global__ __launch_bounds__(64) void scan_serial(
    const float* __restrict__ x,
    const float* __restrict__ A_logs,
    const float* __restrict__ Ds,
    const float* __restrict__ delta,
    const float* __restrict__ Bsb,
    const float* __restrict__ Csb,
    float* __restrict__ ys)
{
    const int chans = D_ / 4;
    int bid = blockIdx.x;
    int bk = bid / chans;
    int d0 = (bid % chans) * 4;
    int b = bk / K_, k = bk % K_;
    int lane = threadIdx.x;
    int g = lane >> 4, n = lane & 15;
    int d = d0 + g;
    int kd = k * D_ + d;

    float A  = -__expf(A_logs[kd * N_ + n]);
    float Dv = Ds[kd];
    const float* dptr = delta + ((long)bk * L_) * D_ + d;
    const float* bptr = Bsb + (long)bk * L_ * N_ + n;
    const float* cptr = Csb + (long)bk * L_ * N_ + n;
    const float* xptr = x + ((long)b * D_ + d) * L_;
    float* yptr = ys + ((long)bk * L_) * D_ + d;

    float h = 0.f;
#pragma unroll 4
    for (int l = 0; l < L_; ++l) {
        float del = dptr[(long)l * D_];
        float u   = xptr[src_idx(k, l)];
        float Bt  = bptr[l * N_];
        float Ct  = cptr[l * N_];
        float dA  = __expf(del * A);
        h = h * dA + del * u * Bt;
        float yv = h * Ct;
        yv += __shfl_xor(yv, 1);
        yv += __shfl_xor(yv, 2);
        yv += __shfl_xor(yv, 4);
        yv += __shfl_xor(yv, 8);
        if (n == 0) yptr[(long)l * D_] = yv + Dv * u;
    }
}

// ---------------------------------------------------------------------------
// Kernel C: cross-merge + LayerNorm. One wave per (b,l) position.
// ---------------------------------------------------------------------------
__global__ __launch_bounds__(256) void merge_ln_kernel(
    const float* __restrict__ ys,
    const float* __restrict__ lnw,
    const float* __restrict__ lnb,
    float* __restrict__ out)
{
    int wid = (blockIdx.x * 256 + threadIdx.x) >> 6;
    int lane = threadIdx.x & 63;
    int b = wid / L_;
    int l = wid % L_;
    int lt = ((l & 63) << 6) | (l >> 6);

    long base0 = ((long)(b * K_ + 0) * L_ + l) * D_;
    long base2 = ((long)(b * K_ + 2) * L_ + (L_ - 1 - l)) * D_;
    long base1 = ((long)(b * K_ + 1) * L_ + lt) * D_;
    long base3 = ((long)(b * K_ + 3) * L_ + (L_ - 1 - lt)) * D_;

    int dA = lane;
    int dB = lane + 64;
    float v0 = ys[base0 + dA] + ys[base2 + dA] + ys[base1 + dA] + ys[base3 + dA];
    float v1 = 0.f;
    if (dB < D_)
        v1 = ys[base0 + dB] + ys[base2 + dB] + ys[base1 + dB] + ys[base3 + dB];

    float s  = v0 + v1;
    float s2 = v0 * v0 + v1 * v1;
#pragma unroll
    for (int m = 1; m < 64; m <<= 1) {
        s  += __shfl_xor(s, m);
        s2 += __shfl_xor(s2, m);
    }
    float mu  = s * (1.f / D_);
    float var = s2 * (1.f / D_) - mu * mu;
    float rstd = rsqrtf(var + 1e-5f);

    long obase = ((long)b * L_ + l) * D_;
    out[obase + dA] = (v0 - mu) * rstd * lnw[dA] + lnb[dA];
    if (dB < D_)
        out[obase + dB] = (v1 - mu) * rstd * lnw[dB] + lnb[dB];
}

extern "C" void kernel_launch(void* const* d_in, const int* in_sizes, int n_in,
                              void* d_out, int out_size, void* d_ws, size_t ws_size,
                              hipStream_t stream) {
    const float* x      = (const float*)d_in[0];
    const float* xpw    = (const float*)d_in[1];
    const float* wdt    = (const float*)d_in[2];
    const float* bdt    = (const float*)d_in[3];
    const float* A_logs = (const float*)d_in[4];
    const float* Ds     = (const float*)d_in[5];
    const float* lnw    = (const float*)d_in[6];
    const float* lnb    = (const float*)d_in[7];
    float* out = (float*)d_out;

    float* ws = (float*)d_ws;
    const long n_delta = (long)B_ * K_ * L_ * D_;     // 6,291,456
    const long n_bc    = (long)B_ * K_ * L_ * N_;     // 1,048,576
    const long n_sum   = (long)S_ * CH_;              // 1,572,864
    float* delta = ws;
    float* xs_t  = delta + n_delta;
    float* Bsb   = xs_t + n_delta;
    float* Csb   = Bsb + n_bc;
    float* ys    = Csb + n_bc;
    float* hharr = ys + n_delta;
    // pAarr aliases ys: pA is dead after scan_combine, ys written only in part2.
    float* pAarr = ys;
    size_t need = (size_t)(n_delta * 3 + n_bc * 2 + n_sum) * sizeof(float); // ~90.3 MB

    if (ws_size >= need) {
        proj_kernel<<<B_ * K_ * (L_ / 64), 256, 0, stream>>>(
            x, xpw, wdt, bdt, delta, xs_t, Bsb, Csb);
        scan_part1<<<B_ * K_ * S_, 192, 0, stream>>>(
            A_logs, delta, xs_t, Bsb, pAarr, hharr);
        scan_combine<<<CH_ / 256, 256, 0, stream>>>(pAarr, hharr);
        scan_part2<<<B_ * K_ * S_, 192, 0, stream>>>(
            A_logs, Ds, delta, xs_t, Bsb, Csb, hharr, ys);
        merge_ln_kernel<<<(B_ * L_) / 4, 256, 0, stream>>>(ys, lnw, lnb, out);
    } else {
        // Fallback: smaller footprint, serial scan.
        float* ys2 = Csb + n_bc;
        proj_kernel<<<B_ * K_ * (L_ / 64), 256, 0, stream>>>(
            x, xpw, wdt, bdt, delta, xs_t, Bsb, Csb);
        scan_serial<<<B_ * K_ * (D_ / 4), 64, 0, stream>>>(
            x, A_logs, Ds, delta, Bsb, Csb, ys2);
        merge_ln_kernel<<<(B_ * L_) / 4, 256, 0, stream>>>(ys2, lnw, lnb, out);
    }
}

// Round 5
// 198.249 us; speedup vs baseline: 9.3768x; 1.0928x over previous
//
#include <hip/hip_runtime.h>
#include <math.h>

#define B_ 4
#define D_ 96
#define H_ 64
#define W_ 64
#define L_ 4096
#define K_ 4
#define N_ 16
#define R_ 6
#define C_ 38   // R + 2N
#define S_ 64   // chunks per sequence
#define CL_ (L_ / S_)  // 64
#define CH_ (B_ * K_ * D_ * N_)  // 24576 scan channels

// Flat index into x[b,d,:,:] (H*W) for cross-scan direction k at sequence pos l.
__device__ __forceinline__ int src_idx(int k, int l) {
    int m = (k >= 2) ? (L_ - 1 - l) : l;
    if (k & 1) {
        return ((m & 63) << 6) | (m >> 6);  // transpose map (H=W=64)
    }
    return m;
}

__device__ __forceinline__ float softplus_f(float a) {
    // exact enough: __expf/__logf are ~2ulp HW ops; for a>15, log1p(e^-a)<4e-7
    return (a > 15.f) ? a : __logf(1.f + __expf(a));
}

// ---------------------------------------------------------------------------
// Kernel A: projections + xs materialization, register-blocked 4x4 GEMM.
// One block (256 thr) per (b,k, 64-l tile).
// W rows permuted at staging: cp = c<6 ? c : c+2  -> dts rows 0..5, Bs cp 8..23,
// Cs cp 24..39; every output group is float4-aligned.
// ---------------------------------------------------------------------------
__global__ __launch_bounds__(256) void proj_kernel(
    const float* __restrict__ x,     // (B,D,H,W)
    const float* __restrict__ xpw,   // (K,38,96)
    const float* __restrict__ wdt,   // (K,96,6)
    const float* __restrict__ bdt,   // (K,96)
    float* __restrict__ delta,       // (B*K, L, 96)
    float* __restrict__ xs_t,        // (B*K, L, 96)
    float* __restrict__ Bsb,         // (B*K, L, 16)
    float* __restrict__ Csb)         // (B*K, L, 16)
{
    const int TL = 64;
    const int tiles = L_ / TL;               // 64
    int bid = blockIdx.x;                    // B*K*tiles = 1024
    int bk = bid / tiles;
    int tile = bid % tiles;
    int b = bk / K_, k = bk % K_;
    int l0 = tile * TL;
    int tid = threadIdx.x;

    __shared__ __align__(16) float s_wpT[D_ * 40];   // [d][cp], 15.4 KB
    __shared__ __align__(16) float s_xs[D_ * TL];    // [d][lt], 24.6 KB
    __shared__ __align__(16) float s_wdt[R_ * D_];   // [r][d], 2.3 KB
    __shared__ __align__(16) float s_bias[D_];
    __shared__ __align__(16) float s_dts[R_ * 68];   // [r][lt] pad68, 1.6 KB

    // --- stage weights ---
    for (int i = tid; i < C_ * D_; i += 256) {
        int d = i / C_, c = i % C_;          // lanes: consecutive c -> LDS banks spread
        int cp = (c < 6) ? c : c + 2;
        s_wpT[d * 40 + cp] = xpw[(k * C_ + c) * D_ + d];
    }
    for (int i = tid; i < 96; i += 256) {    // zero the 2 pad cols (safety)
        s_wpT[i * 40 + 6] = 0.f;
        s_wpT[i * 40 + 7] = 0.f;
    }
    for (int i = tid; i < R_ * D_; i += 256) {
        int r = i / D_, d = i % D_;
        s_wdt[i] = wdt[(k * D_ + d) * R_ + r];
    }
    if (tid < D_) s_bias[tid] = bdt[k * D_ + tid];

    // --- stage xs tile into LDS ---
    long base = (long)bk * L_ + l0;
    if (k & 1) {
        for (int i = tid; i < D_ * TL; i += 256) {
            int d = i >> 6, lt = i & 63;
            int src = (k == 1) ? (lt * 64 + tile) : ((63 - lt) * 64 + (63 - tile));
            s_xs[d * TL + lt] = x[(b * D_ + d) * L_ + src];
        }
    } else {
        for (int i = tid; i < D_ * 16; i += 256) {
            int d = i >> 4, q = i & 15;
            if (k == 0) {
                float4 v = *(const float4*)(x + (b * D_ + d) * L_ + l0 + q * 4);
                *(float4*)(&s_xs[d * TL + q * 4]) = v;
            } else {  // k==2 reversed: s_xs[d][4q+j] = x[.., 4095-l0-4q-j]
                float4 v = *(const float4*)(x + (b * D_ + d) * L_ + (4092 - l0 - q * 4));
                *(float4*)(&s_xs[d * TL + q * 4]) = make_float4(v.w, v.z, v.y, v.x);
            }
        }
    }

    // --- xs_t straight from global (coalesced stores, cached gathers) ---
    for (int i = tid; i < 24 * TL; i += 256) {
        int dq = i % 24, lt = i / 24;
        int d0 = dq * 4;
        int src = src_idx(k, l0 + lt);
        const float* xp = x + (long)b * D_ * L_ + src;
        float4 v = make_float4(xp[(d0 + 0) * L_], xp[(d0 + 1) * L_],
                               xp[(d0 + 2) * L_], xp[(d0 + 3) * L_]);
        *(float4*)(&xs_t[(base + lt) * D_ + d0]) = v;
    }
    __syncthreads();

    // --- GEMM: 4x4 register tiles; 10 c-tiles x 16 lt-tiles = 160 threads ---
    int ct = tid >> 4;
    int lt4 = (tid & 15) * 4;
    if (ct < 10) {
        int cp0 = ct * 4;
        float acc[4][4];
#pragma unroll
        for (int i = 0; i < 4; ++i)
#pragma unroll
            for (int j = 0; j < 4; ++j) acc[i][j] = 0.f;
#pragma unroll 4
        for (int d = 0; d < D_; ++d) {
            float4 wv = *(const float4*)(&s_wpT[d * 40 + cp0]);
            float4 xv = *(const float4*)(&s_xs[d * TL + lt4]);
            float wa[4] = {wv.x, wv.y, wv.z, wv.w};
            float xa[4] = {xv.x, xv.y, xv.z, xv.w};
#pragma unroll
            for (int ci = 0; ci < 4; ++ci)
#pragma unroll
                for (int li = 0; li < 4; ++li)
                    acc[ci][li] += wa[ci] * xa[li];
        }
        if (ct == 0) {
#pragma unroll
            for (int ci = 0; ci < 4; ++ci)
                *(float4*)(&s_dts[ci * 68 + lt4]) =
                    make_float4(acc[ci][0], acc[ci][1], acc[ci][2], acc[ci][3]);
        } else if (ct == 1) {
#pragma unroll
            for (int ci = 0; ci < 2; ++ci)   // cp 4,5 = r4,r5; cp 6,7 discarded
                *(float4*)(&s_dts[(4 + ci) * 68 + lt4]) =
                    make_float4(acc[ci][0], acc[ci][1], acc[ci][2], acc[ci][3]);
        } else if (ct < 6) {
            int n0 = cp0 - 8;
#pragma unroll
            for (int li = 0; li < 4; ++li)
                *(float4*)(&Bsb[(base + lt4 + li) * N_ + n0]) =
                    make_float4(acc[0][li], acc[1][li], acc[2][li], acc[3][li]);
        } else {
            int n0 = cp0 - 24;
#pragma unroll
            for (int li = 0; li < 4; ++li)
                *(float4*)(&Csb[(base + lt4 + li) * N_ + n0]) =
                    make_float4(acc[0][li], acc[1][li], acc[2][li], acc[3][li]);
        }
    }
    __syncthreads();

    // --- delta: 4x4 tiles, lanes d-fastest for coalesced stores ---
    for (int tt = tid; tt < 24 * 16; tt += 256) {
        int dt = tt % 24, lt4b = (tt / 24) * 4;
        int d0 = dt * 4;
        float4 bias = *(const float4*)(&s_bias[d0]);
        float acc[4][4];
#pragma unroll
        for (int li = 0; li < 4; ++li) {
            acc[li][0] = bias.x; acc[li][1] = bias.y;
            acc[li][2] = bias.z; acc[li][3] = bias.w;
        }
#pragma unroll
        for (int r = 0; r < R_; ++r) {
            float4 wv = *(const float4*)(&s_wdt[r * D_ + d0]);
            float4 tv = *(const float4*)(&s_dts[r * 68 + lt4b]);
            float wa[4] = {wv.x, wv.y, wv.z, wv.w};
            float ta[4] = {tv.x, tv.y, tv.z, tv.w};
#pragma unroll
            for (int li = 0; li < 4; ++li)
#pragma unroll
                for (int di = 0; di < 4; ++di)
                    acc[li][di] += ta[li] * wa[di];
        }
#pragma unroll
        for (int li = 0; li < 4; ++li) {
            float4 o = make_float4(softplus_f(acc[li][0]), softplus_f(acc[li][1]),
                                   softplus_f(acc[li][2]), softplus_f(acc[li][3]));
            *(float4*)(&delta[(base + lt4b + li) * D_ + d0]) = o;
        }
    }
}

// ---------------------------------------------------------------------------
// Pass 1: per-chunk local scan (h0=0), register-resident h[8]/pA[8]. No LDS.
// ---------------------------------------------------------------------------
__global__ __launch_bounds__(192) void scan_part1(
    const float* __restrict__ A_logs,
    const float* __restrict__ delta,
    const float* __restrict__ xs_t,
    const float* __restrict__ Bsb,
    float* __restrict__ pAarr,   // [S][CH]
    float* __restrict__ hharr)   // [S][CH]
{
    int bid = blockIdx.x;           // B*K*S = 1024
    int bk = bid / S_;
    int j = bid % S_;
    int tid = threadIdx.x;
    int dd = tid >> 1;              // 0..95
    int half = tid & 1;
    int n0 = half * 8;
    int k = bk % K_;
    int kd = k * D_ + dd;
    int l0 = j * CL_;

    float Av[8];
    {
        const float4* ap = (const float4*)(A_logs + kd * N_ + n0);
        float4 a0 = ap[0], a1 = ap[1];
        Av[0] = -__expf(a0.x); Av[1] = -__expf(a0.y);
        Av[2] = -__expf(a0.z); Av[3] = -__expf(a0.w);
        Av[4] = -__expf(a1.x); Av[5] = -__expf(a1.y);
        Av[6] = -__expf(a1.z); Av[7] = -__expf(a1.w);
    }

    const float* dp = delta + ((long)bk * L_ + l0) * D_ + dd;
    const float* up = xs_t + ((long)bk * L_ + l0) * D_ + dd;
    const float* bp = Bsb + ((long)bk * L_ + l0) * N_ + n0;

    float h[8], pA[8];
#pragma unroll
    for (int i = 0; i < 8; ++i) { h[i] = 0.f; pA[i] = 1.f; }

#pragma unroll 4
    for (int t = 0; t < CL_; ++t) {
        float del = dp[t * D_];
        float u   = up[t * D_];
        float4 b0 = *(const float4*)(bp + t * N_);
        float4 b1 = *(const float4*)(bp + t * N_ + 4);
        float Bv[8] = {b0.x, b0.y, b0.z, b0.w, b1.x, b1.y, b1.z, b1.w};
        float delu = del * u;
#pragma unroll
        for (int i = 0; i < 8; ++i) {
            float dA = __expf(del * Av[i]);
            pA[i] *= dA;
            h[i] = h[i] * dA + delu * Bv[i];
        }
    }

    long sbase = (long)j * CH_ + (long)(bk * D_ + dd) * N_ + n0;
    *(float4*)(pAarr + sbase)     = make_float4(pA[0], pA[1], pA[2], pA[3]);
    *(float4*)(pAarr + sbase + 4) = make_float4(pA[4], pA[5], pA[6], pA[7]);
    *(float4*)(hharr + sbase)     = make_float4(h[0], h[1], h[2], h[3]);
    *(float4*)(hharr + sbase + 4) = make_float4(h[4], h[5], h[6], h[7]);
}

// ---------------------------------------------------------------------------
// Pass 2: sequential combine over S chunk summaries (in-place).
// ---------------------------------------------------------------------------
__global__ __launch_bounds__(256) void scan_combine(
    const float* __restrict__ pAarr,
    float* __restrict__ hharr)
{
    int c = blockIdx.x * 256 + threadIdx.x;  // 0..CH-1
    float h = 0.f;
#pragma unroll 8
    for (int j = 0; j < S_; ++j) {
        long idx = (long)j * CH_ + c;
        float tmp = hharr[idx];
        float pa  = pAarr[idx];
        hharr[idx] = h;
        h = tmp + pa * h;
    }
}

// ---------------------------------------------------------------------------
// Pass 3: re-run each chunk from its true h0, emit y. Register h[8], no LDS.
// ---------------------------------------------------------------------------
__global__ __launch_bounds__(192) void scan_part2(
    const float* __restrict__ A_logs,
    const float* __restrict__ Ds,
    const float* __restrict__ delta,
    const float* __restrict__ xs_t,
    const float* __restrict__ Bsb,
    const float* __restrict__ Csb,
    const float* __restrict__ hharr,
    float* __restrict__ ys)      // (B*K, L, 96)
{
    int bid = blockIdx.x;
    int bk = bid / S_;
    int j = bid % S_;
    int tid = threadIdx.x;
    int dd = tid >> 1;
    int half = tid & 1;
    int n0 = half * 8;
    int k = bk % K_;
    int kd = k * D_ + dd;
    int l0 = j * CL_;

    float Av[8];
    {
        const float4* ap = (const float4*)(A_logs + kd * N_ + n0);
        float4 a0 = ap[0], a1 = ap[1];
        Av[0] = -__expf(a0.x); Av[1] = -__expf(a0.y);
        Av[2] = -__expf(a0.z); Av[3] = -__expf(a0.w);
        Av[4] = -__expf(a1.x); Av[5] = -__expf(a1.y);
        Av[6] = -__expf(a1.z); Av[7] = -__expf(a1.w);
    }
    float Dv = Ds[kd];

    const float* dp = delta + ((long)bk * L_ + l0) * D_ + dd;
    const float* up = xs_t + ((long)bk * L_ + l0) * D_ + dd;
    const float* bp = Bsb + ((long)bk * L_ + l0) * N_ + n0;
    const float* cp = Csb + ((long)bk * L_ + l0) * N_ + n0;
    float* yp = ys + ((long)bk * L_ + l0) * D_ + dd;

    float h[8];
    {
        long sbase = (long)j * CH_ + (long)(bk * D_ + dd) * N_ + n0;
        float4 h0 = *(const float4*)(hharr + sbase);
        float4 h1 = *(const float4*)(hharr + sbase + 4);
        h[0] = h0.x; h[1] = h0.y; h[2] = h0.z; h[3] = h0.w;
        h[4] = h1.x; h[5] = h1.y; h[6] = h1.z; h[7] = h1.w;
    }

#pragma unroll 4
    for (int t = 0; t < CL_; ++t) {
        float del = dp[t * D_];
        float u   = up[t * D_];
        float4 b0 = *(const float4*)(bp + t * N_);
        float4 b1 = *(const float4*)(bp + t * N_ + 4);
        float4 c0 = *(const float4*)(cp + t * N_);
        float4 c1 = *(const float4*)(cp + t * N_ + 4);
        float Bv[8] = {b0.x, b0.y, b0.z, b0.w, b1.x, b1.y, b1.z, b1.w};
        float Cv[8] = {c0.x, c0.y, c0.z, c0.w, c1.x, c1.y, c1.z, c1.w};
        float delu = del * u;
        float y = 0.f;
#pragma unroll
        for (int i = 0; i < 8; ++i) {
            float dA = __expf(del * Av[i]);
            h[i] = h[i] * dA + delu * Bv[i];
            y += h[i] * Cv[i];
        }
        y += __shfl_xor(y, 1);
        if (half == 0) yp[t * D_] = y + Dv * u;
    }
}

// ---------------------------------------------------------------------------
// Serial fallback scan (only if ws_size too small).
// ---------------------------------------------------------------------------
__global__ __launch_bounds__(64) void scan_serial(
    const float* __restrict__ x,
    const float* __restrict__ A_logs,
    const float* __restrict__ Ds,
    const float* __restrict__ delta,
    const float* __restrict__ Bsb,
    const float* __restrict__ Csb,
    float* __restrict__ ys)
{
    const int chans = D_ / 4;
    int bid = blockIdx.x;
    int bk = bid / chans;
    int d0 = (bid % chans) * 4;
    int b = bk / K_, k = bk % K_;
    int lane = threadIdx.x;
    int g = lane >> 4, n = lane & 15;
    int d = d0 + g;
    int kd = k * D_ + d;

    float A  = -__expf(A_logs[kd * N_ + n]);
    float Dv = Ds[kd];
    const float* dptr = delta + ((long)bk * L_) * D_ + d;
    const float* bptr = Bsb + (long)bk * L_ * N_ + n;
    const float* cptr = Csb + (long)bk * L_ * N_ + n;
    const float* xptr = x + ((long)b * D_ + d) * L_;
    float* yptr = ys + ((long)bk * L_) * D_ + d;

    float h = 0.f;
#pragma unroll 4
    for (int l = 0; l < L_; ++l) {
        float del = dptr[(long)l * D_];
        float u   = xptr[src_idx(k, l)];
        float Bt  = bptr[l * N_];
        float Ct  = cptr[l * N_];
        float dA  = __expf(del * A);
        h = h * dA + del * u * Bt;
        float yv = h * Ct;
        yv += __shfl_xor(yv, 1);
        yv += __shfl_xor(yv, 2);
        yv += __shfl_xor(yv, 4);
        yv += __shfl_xor(yv, 8);
        if (n == 0) yptr[(long)l * D_] = yv + Dv * u;
    }
}

// ---------------------------------------------------------------------------
// Kernel C: cross-merge + LayerNorm. One wave per (b,l) position.
// ---------------------------------------------------------------------------
__global__ __launch_bounds__(256) void merge_ln_kernel(
    const float* __restrict__ ys,
    const float* __restrict__ lnw,
    const float* __restrict__ lnb,
    float* __restrict__ out)
{
    int wid = (blockIdx.x * 256 + threadIdx.x) >> 6;
    int lane = threadIdx.x & 63;
    int b = wid / L_;
    int l = wid % L_;
    int lt = ((l & 63) << 6) | (l >> 6);

    long base0 = ((long)(b * K_ + 0) * L_ + l) * D_;
    long base2 = ((long)(b * K_ + 2) * L_ + (L_ - 1 - l)) * D_;
    long base1 = ((long)(b * K_ + 1) * L_ + lt) * D_;
    long base3 = ((long)(b * K_ + 3) * L_ + (L_ - 1 - lt)) * D_;

    int dA = lane;
    int dB = lane + 64;
    float v0 = ys[base0 + dA] + ys[base2 + dA] + ys[base1 + dA] + ys[base3 + dA];
    float v1 = 0.f;
    if (dB < D_)
        v1 = ys[base0 + dB] + ys[base2 + dB] + ys[base1 + dB] + ys[base3 + dB];

    float s  = v0 + v1;
    float s2 = v0 * v0 + v1 * v1;
#pragma unroll
    for (int m = 1; m < 64; m <<= 1) {
        s  += __shfl_xor(s, m);
        s2 += __shfl_xor(s2, m);
    }
    float mu  = s * (1.f / D_);
    float var = s2 * (1.f / D_) - mu * mu;
    float rstd = rsqrtf(var + 1e-5f);

    long obase = ((long)b * L_ + l) * D_;
    out[obase + dA] = (v0 - mu) * rstd * lnw[dA] + lnb[dA];
    if (dB < D_)
        out[obase + dB] = (v1 - mu) * rstd * lnw[dB] + lnb[dB];
}

extern "C" void kernel_launch(void* const* d_in, const int* in_sizes, int n_in,
                              void* d_out, int out_size, void* d_ws, size_t ws_size,
                              hipStream_t stream) {
    const float* x      = (const float*)d_in[0];
    const float* xpw    = (const float*)d_in[1];
    const float* wdt    = (const float*)d_in[2];
    const float* bdt    = (const float*)d_in[3];
    const float* A_logs = (const float*)d_in[4];
    const float* Ds     = (const float*)d_in[5];
    const float* lnw    = (const float*)d_in[6];
    const float* lnb    = (const float*)d_in[7];
    float* out = (float*)d_out;

    float* ws = (float*)d_ws;
    const long n_delta = (long)B_ * K_ * L_ * D_;     // 6,291,456
    const long n_bc    = (long)B_ * K_ * L_ * N_;     // 1,048,576
    const long n_sum   = (long)S_ * CH_;              // 1,572,864
    float* delta = ws;
    float* xs_t  = delta + n_delta;
    float* Bsb   = xs_t + n_delta;
    float* Csb   = Bsb + n_bc;
    float* ys    = Csb + n_bc;
    float* hharr = ys + n_delta;
    // pAarr aliases ys: pA is dead after scan_combine, ys written only in part2.
    float* pAarr = ys;
    size_t need = (size_t)(n_delta * 3 + n_bc * 2 + n_sum) * sizeof(float); // ~90.3 MB

    if (ws_size >= need) {
        proj_kernel<<<B_ * K_ * (L_ / 64), 256, 0, stream>>>(
            x, xpw, wdt, bdt, delta, xs_t, Bsb, Csb);
        scan_part1<<<B_ * K_ * S_, 192, 0, stream>>>(
            A_logs, delta, xs_t, Bsb, pAarr, hharr);
        scan_combine<<<CH_ / 256, 256, 0, stream>>>(pAarr, hharr);
        scan_part2<<<B_ * K_ * S_, 192, 0, stream>>>(
            A_logs, Ds, delta, xs_t, Bsb, Csb, hharr, ys);
        merge_ln_kernel<<<(B_ * L_) / 4, 256, 0, stream>>>(ys, lnw, lnb, out);
    } else {
        // Fallback: smaller footprint, serial scan.
        float* ys2 = Csb + n_bc;
        proj_kernel<<<B_ * K_ * (L_ / 64), 256, 0, stream>>>(
            x, xpw, wdt, bdt, delta, xs_t, Bsb, Csb);
        scan_serial<<<B_ * K_ * (D_ / 4), 64, 0, stream>>>(
            x, A_logs, Ds, delta, Bsb, Csb, ys2);
        merge_ln_kernel<<<(B_ * L_) / 4, 256, 0, stream>>>(ys2, lnw, lnb, out);
    }
}